// Round 14
// baseline (2082.028 us; speedup 1.0000x reference)
//
#include <hip/hip_runtime.h>
#include <hip/hip_bf16.h>
#include <math.h>

// ---- JAX threefry RNG: partitionable, bits = o0 ^ o1 [VERIFIED round 2] ----

typedef short short8 __attribute__((ext_vector_type(8)));
typedef float f32x4 __attribute__((ext_vector_type(4)));
typedef unsigned int uint;

__host__ __device__ inline void tf2x32(unsigned k0, unsigned k1,
                                       unsigned x0, unsigned x1,
                                       unsigned& o0, unsigned& o1) {
  unsigned ks2 = k0 ^ k1 ^ 0x1BD11BDAu;
#define TF_R(x, r) x0 += x1; x1 = ((x1 << (r)) | (x1 >> (32 - (r)))); x1 ^= x0;
  x0 += k0; x1 += k1;
  TF_R(x1,13) TF_R(x1,15) TF_R(x1,26) TF_R(x1,6)
  x0 += k1; x1 += ks2 + 1u;
  TF_R(x1,17) TF_R(x1,29) TF_R(x1,16) TF_R(x1,24)
  x0 += ks2; x1 += k0 + 2u;
  TF_R(x1,13) TF_R(x1,15) TF_R(x1,26) TF_R(x1,6)
  x0 += k0; x1 += k1 + 3u;
  TF_R(x1,17) TF_R(x1,29) TF_R(x1,16) TF_R(x1,24)
  x0 += k1; x1 += ks2 + 4u;
  TF_R(x1,13) TF_R(x1,15) TF_R(x1,26) TF_R(x1,6)
  x0 += ks2; x1 += k0 + 5u;
#undef TF_R
  o0 = x0; o1 = x1;
}

// ---------------- bf16x2 plane machinery ----------------
// fp32 matrix [M][K] row-major -> 2 bf16 planes (hi/mid) in MFMA
// fragment-tile order: plane[tile16_m][kblock32][lane64][8 bf16], where
// lane = ((k>>3)&3)*16 + (m&15), j = k&7.  Tile = 1024 B contiguous.
// 3-term product (hh, hm, mh): dropped terms ~5e-6 abs << 0.0078 slack.

__device__ inline unsigned bsplit(float x, float y, float& rx, float& ry) {
  union { __hip_bfloat162 h; unsigned u; } c;
  c.h = __float22bfloat162_rn(make_float2(x, y));
  rx = x - __uint_as_float(c.u << 16);
  ry = y - __uint_as_float(c.u & 0xffff0000u);
  return c.u;
}

__device__ inline void split2u(float4 v0, float4 v1, uint4& H, uint4& M) {
  float r[8]; float d0, d1;
  H.x = bsplit(v0.x, v0.y, r[0], r[1]);
  H.y = bsplit(v0.z, v0.w, r[2], r[3]);
  H.z = bsplit(v1.x, v1.y, r[4], r[5]);
  H.w = bsplit(v1.z, v1.w, r[6], r[7]);
  M.x = bsplit(r[0], r[1], d0, d1);
  M.y = bsplit(r[2], r[3], d0, d1);
  M.z = bsplit(r[4], r[5], d0, d1);
  M.w = bsplit(r[6], r[7], d0, d1);
}

__global__ void k_idx(int* __restrict__ idx, unsigned k2a, unsigned k2b,
                      int n, int mask) {
  int j = blockIdx.x * 256 + threadIdx.x;
  if (j >= n) return;
  unsigned o0, o1;
  tf2x32(k2a, k2b, 0u, (unsigned)j, o0, o1);
  idx[j] = (int)((o0 ^ o1) & (unsigned)mask);
}

// positional-encoding table via fp64 rotation recurrence: thread owns one
// d-pair and a 16-row strip; 2 sincos + 16x4 f64 FMA replaces 16 sincos.
// Rotation error ~1e-14 << f32 table rounding -> matches fp64 path exactly.
__global__ __launch_bounds__(256) void k_pe(float* __restrict__ pe) {
  int d2 = threadIdx.x;            // 0..255 (d-pair)
  int l0 = blockIdx.x * 16;        // 256 blocks x 16 rows
  double th = exp((double)(2 * d2) * (-9.210340371976184 / 512.0));
  double sT = sin(th), cT = cos(th);
  double a = (double)l0 * th;
  double s = sin(a), c = cos(a);
  float* row = pe + (size_t)l0 * 512 + 2 * d2;
#pragma unroll
  for (int i = 0; i < 16; i++) {
    row[0] = (float)s; row[1] = (float)c;
    double ns = s * cT + c * sT;
    double nc = c * cT - s * sT;
    s = ns; c = nc;
    row += 512;
  }
}

// h = x @ emb_w^T + emb_b + pe   (K=64, 16 rows per block)
__global__ __launch_bounds__(256) void k_embed(const float* __restrict__ x,
    const float* __restrict__ W, const float* __restrict__ eb,
    const float* __restrict__ pe, float* __restrict__ out) {
  __shared__ __align__(16) float xs[16][64];
  int r0 = blockIdx.x * 16;
  int t = threadIdx.x;
  ((float4*)&xs[0][0])[t] = ((const float4*)(x + (size_t)r0 * 64))[t];
  __syncthreads();
  int d0 = t, d1 = t + 256;
  float acc0[16], acc1[16];
#pragma unroll
  for (int r = 0; r < 16; r++) { acc0[r] = 0.f; acc1[r] = 0.f; }
  for (int k = 0; k < 64; k++) {
    float w0 = W[d0 * 64 + k], w1 = W[d1 * 64 + k];
#pragma unroll
    for (int r = 0; r < 16; r++) {
      float xv = xs[r][k];
      acc0[r] = fmaf(xv, w0, acc0[r]);
      acc1[r] = fmaf(xv, w1, acc1[r]);
    }
  }
  float eb0 = eb[d0], eb1 = eb[d1];
#pragma unroll
  for (int r = 0; r < 16; r++) {
    int row = r0 + r;
    int l = row & 4095;
    out[(size_t)row * 512 + d0] = acc0[r] + eb0 + pe[(size_t)l * 512 + d0];
    out[(size_t)row * 512 + d1] = acc1[r] + eb1 + pe[(size_t)l * 512 + d1];
  }
}

// column-mean phase 1: per-(seg,bh) fp64 partial sums (grid saturates CUs)
__global__ __launch_bounds__(256) void k_colmean1(const float* __restrict__ X,
    double* __restrict__ part, int L, int S) {
  int seg = blockIdx.x, bh = blockIdx.y, b = bh >> 3, h = bh & 7;
  int w = threadIdx.x >> 6, d = threadIdx.x & 63;
  int rows = L / S, r0 = seg * rows;
  const float* base = X + (size_t)b * L * 512 + h * 64 + d;
  double s = 0.0;
  for (int l = r0 + w; l < r0 + rows; l += 4) s += (double)base[(size_t)l * 512];
  __shared__ double red[4][64];
  red[w][d] = s;
  __syncthreads();
  if (w == 0)
    part[((size_t)bh * S + seg) * 64 + d] =
        red[0][d] + red[1][d] + red[2][d] + red[3][d];
}

// column-mean phase 2: reduce S segments, divide by L
__global__ void k_colmean2(const double* __restrict__ part,
    float* __restrict__ meanq, int L, int S) {
  int bh = blockIdx.x, d = threadIdx.x;
  const double* p = part + (size_t)bh * S * 64 + d;
  double s = 0.0;
  for (int seg = 0; seg < S; seg++) s += p[seg * 64];
  meanq[bh * 64 + d] = (float)(s / (double)L);
}

// M[b,h,l] = max_s dot(q_l,k_s) - sum_s(...)/L.  Pure f32 (round-2 numerics).
// ROUND-6 VARIANT (best measured: 155us, occ 83%): 4 lanes per gathered row,
// 12 gathers issued up-front for ILP, barrier after qs staging.
__global__ __launch_bounds__(256) void k_M(const float* __restrict__ X,
    const int* __restrict__ idx, float* __restrict__ Mout, int L, int Lsh,
    int u, float invL) {
  int w = threadIdx.x >> 6, lane = threadIdx.x & 63;
  int gl = blockIdx.x * 4 + w;
  int l = gl & (L - 1), bh = gl >> Lsh, b = bh >> 3, h = bh & 7;
  const float* Xbh = X + (size_t)b * L * 512 + h * 64;
  __shared__ float qs[4][64];
  qs[w][lane] = Xbh[(size_t)l * 512 + lane];
  __syncthreads();
  const int s16 = lane >> 2, j = lane & 3;
  float4 qv[4];
#pragma unroll
  for (int c = 0; c < 4; c++) qv[c] = *(const float4*)&qs[w][c * 16 + j * 4];
  const int base = l * u;
  int kx[3];
#pragma unroll
  for (int g = 0; g < 3; g++) {
    int s = g * 16 + s16;
    kx[g] = (s < u) ? idx[base + s] : 0;
  }
  float4 kv[3][4];
#pragma unroll
  for (int g = 0; g < 3; g++) {
    const float* row = Xbh + (size_t)kx[g] * 512 + j * 4;
#pragma unroll
    for (int c = 0; c < 4; c++) kv[g][c] = *(const float4*)(row + c * 16);
  }
  float mv = -1e30f, sv = 0.f;
#pragma unroll
  for (int g = 0; g < 3; g++) {
    float pc[4];
#pragma unroll
    for (int c = 0; c < 4; c++) {
      float p = qv[c].x * kv[g][c].x;
      p = fmaf(qv[c].y, kv[g][c].y, p);
      p = fmaf(qv[c].z, kv[g][c].z, p);
      p = fmaf(qv[c].w, kv[g][c].w, p);
      pc[c] = p;
    }
    float d = (pc[0] + pc[1]) + (pc[2] + pc[3]);
    d += __shfl_xor(d, 1);
    d += __shfl_xor(d, 2);          // all 4 j-lanes now hold dot_s
    if (g * 16 + s16 < u) { mv = fmaxf(mv, d); sv += d; }
  }
  for (int off = 4; off < 64; off <<= 1) {
    mv = fmaxf(mv, __shfl_xor(mv, off));
    sv += __shfl_xor(sv, off);
  }
  if (lane == 0) Mout[(size_t)bh * L + l] = mv - sv * invL;
}

// iterative top-u argmax per (b,h); tie -> smaller index (matches lax.top_k).
// Cached per-thread local max; only the winner's owner rescans its strided
// chunk. Wave shfl tree + 2 barriers/iter.
__global__ __launch_bounds__(256) void k_topk(const float* __restrict__ M,
    int* __restrict__ top, int L, int u) {
  __shared__ float mv[4096];
  __shared__ float wv[4];
  __shared__ int wi[4];
  __shared__ int bi_s;
  int bh = blockIdx.x, t = threadIdx.x;
  int w = t >> 6, lane = t & 63;
  const float* Mr = M + (size_t)bh * L;
  for (int k = t; k < L; k += 256) mv[k] = Mr[k];
  __syncthreads();
  float lv = -1e30f; int li = 0x7fffffff;
  for (int k = t; k < L; k += 256) {
    float v = mv[k];
    if (v > lv) { lv = v; li = k; }   // ascending k -> earliest on ties
  }
  for (int it = 0; it < u; it++) {
    float v = lv; int i = li;
#pragma unroll
    for (int off = 1; off < 64; off <<= 1) {
      float v2 = __shfl_xor(v, off); int i2 = __shfl_xor(i, off);
      if (v2 > v || (v2 == v && i2 < i)) { v = v2; i = i2; }
    }
    if (lane == 0) { wv[w] = v; wi[w] = i; }
    __syncthreads();
    if (t == 0) {
      float bv = wv[0]; int bi = wi[0];
#pragma unroll
      for (int jj = 1; jj < 4; jj++) {
        if (wv[jj] > bv || (wv[jj] == bv && wi[jj] < bi)) { bv = wv[jj]; bi = wi[jj]; }
      }
      top[bh * u + it] = bi;
      mv[bi] = -1e30f;
      bi_s = bi;
    }
    __syncthreads();
    int bi = bi_s;
    if ((bi & 255) == t) {            // owner refreshes its cached local max
      lv = -1e30f; li = 0x7fffffff;
      for (int k = t; k < L; k += 256) {
        float v = mv[k];
        if (v > lv) { lv = v; li = k; }
      }
    }
  }
}

// S[bh,ur,k] = scale * dot(q_red[ur], q_k) for 64-k tile per block
__global__ __launch_bounds__(256) void k_scores(const float* __restrict__ X,
    const int* __restrict__ top, float* __restrict__ S, int L, int u) {
  __shared__ __align__(16) float ktT[64][68];
  __shared__ __align__(16) float qred[48][64];
  int bh = blockIdx.y, b = bh >> 3, h = bh & 7;
  int k0 = blockIdx.x * 64;
  int t = threadIdx.x;
  const float* Xbh = X + (size_t)b * L * 512 + h * 64;
#pragma unroll
  for (int it = 0; it < 4; it++) {
    int lin = t + it * 256;                // (kk, fi) over 64x16
    int kk = lin >> 4, fi = lin & 15;
    float4 v = *(const float4*)(Xbh + (size_t)(k0 + kk) * 512 + fi * 4);
    ktT[fi * 4 + 0][kk] = v.x; ktT[fi * 4 + 1][kk] = v.y;
    ktT[fi * 4 + 2][kk] = v.z; ktT[fi * 4 + 3][kk] = v.w;
  }
#pragma unroll
  for (int it = 0; it < 3; it++) {
    int lin = t + it * 256;                // (ur, fi) over 48x16
    int ur = lin >> 4, fi = lin & 15;
    if (ur < u) {
      int row = top[bh * u + ur];
      *(float4*)(&qred[ur][fi * 4]) = *(const float4*)(Xbh + (size_t)row * 512 + fi * 4);
    } else if (ur < 48) {
      *(float4*)(&qred[ur][fi * 4]) = make_float4(0.f, 0.f, 0.f, 0.f);
    }
  }
  __syncthreads();
  int xq = t & 15, y = t >> 4;
  float acc[3][4];
#pragma unroll
  for (int j = 0; j < 3; j++)
#pragma unroll
    for (int e = 0; e < 4; e++) acc[j][e] = 0.f;
  for (int d = 0; d < 64; d++) {
    float4 kv = *(const float4*)(&ktT[d][xq * 4]);
#pragma unroll
    for (int j = 0; j < 3; j++) {
      float qv = qred[y * 3 + j][d];
      acc[j][0] = fmaf(qv, kv.x, acc[j][0]);
      acc[j][1] = fmaf(qv, kv.y, acc[j][1]);
      acc[j][2] = fmaf(qv, kv.z, acc[j][2]);
      acc[j][3] = fmaf(qv, kv.w, acc[j][3]);
    }
  }
#pragma unroll
  for (int j = 0; j < 3; j++) {
    int ur = y * 3 + j;
    if (ur < u) {
      float4 o = make_float4(acc[j][0] * 0.125f, acc[j][1] * 0.125f,
                             acc[j][2] * 0.125f, acc[j][3] * 0.125f);
      *(float4*)(S + ((size_t)(bh * u + ur)) * L + k0 + xq * 4) = o;
    }
  }
}

// PV partials, flash-style: block=(seg,bh) computes per-ur SEGMENT-local max
// (pre-pass over its own S slice; slice then L2-hot for the weight pass),
// accumulates acc = sum_l exp(s - m_seg) * x  and  esum = sum_l exp(s - m_seg).
// k_pvred combines segments with exp(m_seg - mx) factors (max of seg-maxes
// == global max exactly).
#define PVSEG 8
__global__ __launch_bounds__(256) void k_pv(const float* __restrict__ X,
    const float* __restrict__ S, float* __restrict__ P2,
    float* __restrict__ MS, float* __restrict__ SS, int L, int u) {
  __shared__ __align__(16) float xs[32][64];
  __shared__ __align__(16) float wsm[32][52];   // pad 48->52 (bank spread)
  int seg = blockIdx.x, bh = blockIdx.y, b = bh >> 3, h = bh & 7;
  int t = threadIdx.x, w = t >> 6, lane = t & 63;
  int rows = L / PVSEG, l0 = seg * rows;
  const float* Xb = X + (size_t)b * L * 512 + h * 64;
  int li = lane & 31, par = lane >> 5;
  const float* Sp[6]; int val[6];
#pragma unroll
  for (int jj = 0; jj < 6; jj++) {
    int ur = w * 12 + par + jj * 2;
    val[jj] = (ur < u);
    Sp[jj] = S + (size_t)(bh * u + (val[jj] ? ur : 0)) * L + l0 + li;
  }
  // pass 1: segment-local max per ur (32 li-lanes cover rows); doubles as
  // L2 prefetch of this block's S slice for the weight pass below.
  float mloc[6];
#pragma unroll
  for (int jj = 0; jj < 6; jj++) mloc[jj] = -1e30f;
  for (int c = 0; c < rows; c += 32) {
#pragma unroll
    for (int jj = 0; jj < 6; jj++) mloc[jj] = fmaxf(mloc[jj], Sp[jj][c]);
  }
#pragma unroll
  for (int jj = 0; jj < 6; jj++) {
#pragma unroll
    for (int off = 1; off < 32; off <<= 1)
      mloc[jj] = fmaxf(mloc[jj], __shfl_xor(mloc[jj], off));
  }
  float acc[12], esum[6];
#pragma unroll
  for (int j = 0; j < 12; j++) acc[j] = 0.f;
#pragma unroll
  for (int j = 0; j < 6; j++) esum[j] = 0.f;
  int xr = t >> 4, xf = t & 15;
  for (int c = 0; c < rows; c += 32) {
    __syncthreads();
    *(float4*)&xs[xr][xf * 4] =
        *(const float4*)(Xb + (size_t)(l0 + c + xr) * 512 + xf * 4);
    *(float4*)&xs[16 + xr][xf * 4] =
        *(const float4*)(Xb + (size_t)(l0 + c + 16 + xr) * 512 + xf * 4);
#pragma unroll
    for (int jj = 0; jj < 6; jj++) {
      float e = val[jj] ? expf(Sp[jj][c] - mloc[jj]) : 0.f;
      esum[jj] += e;
      wsm[li][w * 12 + par + jj * 2] = e;
    }
    __syncthreads();
#pragma unroll 2
    for (int l = 0; l < 32; l++) {
      float xv = xs[l][lane];
      float4 w0 = *(const float4*)&wsm[l][w * 12];
      float4 w1 = *(const float4*)&wsm[l][w * 12 + 4];
      float4 w2 = *(const float4*)&wsm[l][w * 12 + 8];
      acc[0]  = fmaf(w0.x, xv, acc[0]);  acc[1]  = fmaf(w0.y, xv, acc[1]);
      acc[2]  = fmaf(w0.z, xv, acc[2]);  acc[3]  = fmaf(w0.w, xv, acc[3]);
      acc[4]  = fmaf(w1.x, xv, acc[4]);  acc[5]  = fmaf(w1.y, xv, acc[5]);
      acc[6]  = fmaf(w1.z, xv, acc[6]);  acc[7]  = fmaf(w1.w, xv, acc[7]);
      acc[8]  = fmaf(w2.x, xv, acc[8]);  acc[9]  = fmaf(w2.y, xv, acc[9]);
      acc[10] = fmaf(w2.z, xv, acc[10]); acc[11] = fmaf(w2.w, xv, acc[11]);
    }
  }
  float* P = P2 + ((size_t)(bh * PVSEG + seg) * 48 + w * 12) * 64 + lane;
#pragma unroll
  for (int j = 0; j < 12; j++) P[j * 64] = acc[j];
#pragma unroll
  for (int jj = 0; jj < 6; jj++) {
    float es = esum[jj];
#pragma unroll
    for (int off = 1; off < 32; off <<= 1) es += __shfl_xor(es, off);
    if (li == 0) {
      int ur = w * 12 + par + jj * 2;
      MS[((size_t)bh * PVSEG + seg) * 48 + ur] = mloc[jj];
      SS[((size_t)bh * PVSEG + seg) * 48 + ur] = es;
    }
  }
}

// combine segments: mx = max_seg m_seg; den = sum_seg esum_seg*exp(m_seg-mx);
// ctx = sum_seg acc_seg*exp(m_seg-mx) / den. Writes compact CTX + FLG=ur+1.
__global__ __launch_bounds__(256) void k_pvred(const float* __restrict__ P2,
    const float* __restrict__ MS, const float* __restrict__ SS,
    const int* __restrict__ top, float* __restrict__ CTX,
    char* __restrict__ FLG, int L, int u) {
  int bh = blockIdx.x;
  int t = threadIdx.x;
  const float* Pb = P2 + (size_t)bh * PVSEG * 48 * 64;
  const float* Mb = MS + (size_t)bh * PVSEG * 48;
  const float* Sb = SS + (size_t)bh * PVSEG * 48;
  __shared__ float fac[PVSEG][48];
  __shared__ double dens[48];
  if (t < u) {
    float mx = Mb[t];
#pragma unroll
    for (int s = 1; s < PVSEG; s++) mx = fmaxf(mx, Mb[s * 48 + t]);
    double den = 0.0;
#pragma unroll
    for (int s = 0; s < PVSEG; s++) {
      float f = expf(Mb[s * 48 + t] - mx);
      fac[s][t] = f;
      den += (double)Sb[s * 48 + t] * (double)f;
    }
    dens[t] = den;
  }
  __syncthreads();
  for (int e = t; e < u * 64; e += 256) {
    int ur = e >> 6, d = e & 63;
    const float* p = Pb + ur * 64 + d;
    const int st = 48 * 64;
    double num = 0.0;
#pragma unroll
    for (int s = 0; s < PVSEG; s++)
      num += (double)p[s * st] * (double)fac[s][ur];
    double tot = num / dens[ur];
    CTX[((size_t)bh * 48 + ur) * 64 + d] = (float)tot;
    if (d == 0) FLG[(size_t)bh * L + top[bh * u + ur]] = (char)(ur + 1);
  }
}

// X <- LN(X + ctx) * gs + gb, in place, AND emit bf16x2 planes of the result
// into the (dead) A region, chunk-local frag order (replaces k_splitX(X)).
// One wave per row; lane owns 8 consecutive cols (d = lane*8 + i), so each
// lane emits one H/Md uint4 pair. ctx from compact CTX via FLG (=ur+1).
__global__ __launch_bounds__(256) void k_ln1(float* __restrict__ X,
    const char* __restrict__ FLG, const float* __restrict__ CTX,
    const float* __restrict__ meanq, const float* __restrict__ gs,
    const float* __restrict__ gb, char* __restrict__ XPbase, int L, int Lsh) {
  int w = threadIdx.x >> 6, lane = threadIdx.x & 63;
  int row = blockIdx.x * 4 + w;
  int b = row >> Lsh, l = row & (L - 1);
  float* xr = X + (size_t)row * 512;
  int h = lane >> 3;                          // head of this lane's 8 cols
  int bh = b * 8 + h;
  int flag = (int)FLG[(size_t)bh * L + l];    // 0 or ur+1
  float4 c0, c1;
  if (flag) {
    const float* cx = CTX + ((size_t)bh * 48 + (flag - 1)) * 64 + (lane & 7) * 8;
    c0 = *(const float4*)cx; c1 = *(const float4*)(cx + 4);
  } else {
    const float* mq = meanq + b * 512 + lane * 8;
    c0 = *(const float4*)mq; c1 = *(const float4*)(mq + 4);
  }
  float4 x0 = *(const float4*)(xr + lane * 8);
  float4 x1 = *(const float4*)(xr + lane * 8 + 4);
  float v[8] = { x0.x + c0.x, x0.y + c0.y, x0.z + c0.z, x0.w + c0.w,
                 x1.x + c1.x, x1.y + c1.y, x1.z + c1.z, x1.w + c1.w };
  double s = 0.0, s2 = 0.0;
#pragma unroll
  for (int i = 0; i < 8; i++) { s += (double)v[i]; s2 += (double)v[i] * (double)v[i]; }
  for (int off = 32; off; off >>= 1) { s += __shfl_xor(s, off); s2 += __shfl_xor(s2, off); }
  double mu = s * (1.0 / 512.0);
  double var = s2 * (1.0 / 512.0) - mu * mu;
  float rsd = (float)(1.0 / sqrt(var + 1e-5));
  float muf = (float)mu;
  float4 g0 = *(const float4*)(gs + lane * 8);
  float4 g1 = *(const float4*)(gs + lane * 8 + 4);
  float4 b0 = *(const float4*)(gb + lane * 8);
  float4 b1 = *(const float4*)(gb + lane * 8 + 4);
  float4 y0 = make_float4((v[0] - muf) * rsd * g0.x + b0.x,
                          (v[1] - muf) * rsd * g0.y + b0.y,
                          (v[2] - muf) * rsd * g0.z + b0.z,
                          (v[3] - muf) * rsd * g0.w + b0.w);
  float4 y1 = make_float4((v[4] - muf) * rsd * g1.x + b1.x,
                          (v[5] - muf) * rsd * g1.y + b1.y,
                          (v[6] - muf) * rsd * g1.z + b1.z,
                          (v[7] - muf) * rsd * g1.w + b1.w);
  *(float4*)(xr + lane * 8) = y0;
  *(float4*)(xr + lane * 8 + 4) = y1;
  // planes, chunk-local (8192-row chunks inside A region)
  int c = row >> 13, ml = row & 8191;
  char* P = XPbase + ((size_t)c << 24);       // 16 MiB per chunk
  const size_t psz = (size_t)8192 * 512 * 2;  // 8 MiB per plane
  int k = lane * 8;
  size_t off = ((size_t)(ml >> 4) * 16 + (k >> 5)) * 1024
             + (size_t)(((k >> 3) & 3) * 256 + (ml & 15) * 16);
  uint4 H, Md;
  split2u(y0, y1, H, Md);
  *(uint4*)(P + off) = H;
  *(uint4*)(P + psz + off) = Md;
}

// out <- LN(X + Y2) with pair-pool (distil); one wave per output row
__global__ __launch_bounds__(256) void k_ln2(const float* __restrict__ X,
    const float* __restrict__ Y2, const float* __restrict__ gs,
    const float* __restrict__ gb, float* __restrict__ out) {
  int w = threadIdx.x >> 6, lane = threadIdx.x & 63;
  int orow = blockIdx.x * 4 + w;
  float o[8] = {0.f,0.f,0.f,0.f,0.f,0.f,0.f,0.f};
  for (int p = 0; p < 2; p++) {
    int row = orow * 2 + p;
    const float* xr = X + (size_t)row * 512;
    const float* yr = Y2 + (size_t)row * 512;
    float v[8]; double s = 0.0, s2 = 0.0;
#pragma unroll
    for (int i = 0; i < 8; i++) {
      float val = xr[lane + i * 64] + yr[lane + i * 64];
      v[i] = val; s += (double)val; s2 += (double)val * (double)val;
    }
    for (int off = 32; off; off >>= 1) { s += __shfl_xor(s, off); s2 += __shfl_xor(s2, off); }
    double mu = s * (1.0 / 512.0);
    double var = s2 * (1.0 / 512.0) - mu * mu;
    float rsd = (float)(1.0 / sqrt(var + 1e-5));
    float muf = (float)mu;
#pragma unroll
    for (int i = 0; i < 8; i++)
      o[i] += (v[i] - muf) * rsd * gs[lane + i * 64] + gb[lane + i * 64];
  }
#pragma unroll
  for (int i = 0; i < 8; i++)
    out[(size_t)orow * 512 + lane + i * 64] = o[i] * 0.5f;
}

// final LN (no pool) emitting bf16x2 planes directly (M = 8192, K = 512);
// lane owns 8 consecutive cols. Replaces fp32 store + k_splitX.
__global__ __launch_bounds__(256) void k_ln2p(const float* __restrict__ X,
    const float* __restrict__ Y2, const float* __restrict__ gs,
    const float* __restrict__ gb, char* __restrict__ P) {
  int w = threadIdx.x >> 6, lane = threadIdx.x & 63;
  int row = blockIdx.x * 4 + w;
  const float* xr = X + (size_t)row * 512;
  const float* yr = Y2 + (size_t)row * 512;
  float4 x0 = *(const float4*)(xr + lane * 8);
  float4 x1 = *(const float4*)(xr + lane * 8 + 4);
  float4 z0 = *(const float4*)(yr + lane * 8);
  float4 z1 = *(const float4*)(yr + lane * 8 + 4);
  float v[8] = { x0.x + z0.x, x0.y + z0.y, x0.z + z0.z, x0.w + z0.w,
                 x1.x + z1.x, x1.y + z1.y, x1.z + z1.z, x1.w + z1.w };
  double s = 0.0, s2 = 0.0;
#pragma unroll
  for (int i = 0; i < 8; i++) { s += (double)v[i]; s2 += (double)v[i] * (double)v[i]; }
  for (int off = 32; off; off >>= 1) { s += __shfl_xor(s, off); s2 += __shfl_xor(s2, off); }
  double mu = s * (1.0 / 512.0);
  double var = s2 * (1.0 / 512.0) - mu * mu;
  float rsd = (float)(1.0 / sqrt(var + 1e-5));
  float muf = (float)mu;
  float4 g0 = *(const float4*)(gs + lane * 8);
  float4 g1 = *(const float4*)(gs + lane * 8 + 4);
  float4 b0 = *(const float4*)(gb + lane * 8);
  float4 b1 = *(const float4*)(gb + lane * 8 + 4);
  float4 y0 = make_float4((v[0] - muf) * rsd * g0.x + b0.x,
                          (v[1] - muf) * rsd * g0.y + b0.y,
                          (v[2] - muf) * rsd * g0.z + b0.z,
                          (v[3] - muf) * rsd * g0.w + b0.w);
  float4 y1 = make_float4((v[4] - muf) * rsd * g1.x + b1.x,
                          (v[5] - muf) * rsd * g1.y + b1.y,
                          (v[6] - muf) * rsd * g1.z + b1.z,
                          (v[7] - muf) * rsd * g1.w + b1.w);
  const size_t psz = (size_t)8192 * 512 * 2;
  int k = lane * 8;
  size_t off = ((size_t)(row >> 4) * 16 + (k >> 5)) * 1024
             + (size_t)(((k >> 3) & 3) * 256 + (row & 15) * 16);
  uint4 H, Md;
  split2u(y0, y1, H, Md);
  *(uint4*)(P + off) = H;
  *(uint4*)(P + psz + off) = Md;
}

// split fp32 [M][K] -> 2 planes frag-tile order. total8 = M*K/8. (weights)
__global__ void k_splitX(const float* __restrict__ X, char* __restrict__ P,
                         int K, int total8) {
  int f = blockIdx.x * 256 + threadIdx.x;
  if (f >= total8) return;
  int k8 = f % (K >> 3), m = f / (K >> 3);
  int k = k8 * 8;
  const float* src = X + (size_t)m * K + k;
  float4 v0 = *(const float4*)(src);
  float4 v1 = *(const float4*)(src + 4);
  uint4 H, Md;
  split2u(v0, v1, H, Md);
  size_t psz = (size_t)total8 * 16;   // M*K*2 bytes per plane
  size_t off = ((size_t)(m >> 4) * (K >> 5) + (k >> 5)) * 1024
             + (size_t)(((k >> 3) & 3) * 256 + (m & 15) * 16);
  *(uint4*)(P + off) = H;
  *(uint4*)(P + psz + off) = Md;
}

__device__ __forceinline__ void async16(void* lds, const void* g) {
  __builtin_amdgcn_global_load_lds(
      (const __attribute__((address_space(1))) uint*)g,
      (__attribute__((address_space(3))) uint*)lds, 16, 0, 0);
}

// C = A @ B^T + bias, A/B as bf16x2 frag-order planes. 3-term bf16x2
// (hh, hm, mh). Block tile: (MT*16) x 128, BK=32. 4 waves as 2x2.
// COUNTED-VMCNT DEPTH-DEEP PIPELINE (T3/T4): DEPTH LDS buffers, raw
// s_barrier + inline-asm counted vmcnt so (DEPTH-1) stages of
// global_load_lds stay in flight across barriers. DEPTH=3 for MT=4
// (72KB LDS, 2 blocks/CU) doubles the latency-hiding window vs DEPTH=2
// (in-flight ~2 phases, covers L2 + much of HBM latency). MT=8 stays
// DEPTH=2 (3 would cost 96KB -> 1 block/CU). Steady-state wait after
// MFMA: vmcnt((DEPTH-1)*LPW) -> kt+1's stage complete, later ones in
// flight. Tail drains ladder LPW*2 -> LPW -> 0. Math identical to the
// plain loop (same MFMA order) -> bit-identical C.
// XCD-aware chunked swizzle (T1). PLANES_OUT epilogue unchanged.
template <int MT, int GELU, int PLANES_OUT, int DEPTH>
__global__ __launch_bounds__(256) void k_gemm6(const char* __restrict__ AP,
    const char* __restrict__ BP, const float* __restrict__ bias,
    void* __restrict__ Cout, int N, int K) {
  constexpr int NT = MT * 2 + 16;           // tiles per K-step (A + B)
  constexpr int LPW = (MT == 8) ? 8 : 6;    // loads per wave per stage
  __shared__ __align__(16) char lds[DEPTH * NT * 1024];
  const int t = threadIdx.x;
  const int w = t >> 6, lane = t & 63;
  int lin = blockIdx.y * gridDim.x + blockIdx.x;
  const int nb = gridDim.x * gridDim.y;
  lin = (lin & 7) * (nb >> 3) + (lin >> 3);   // XCD chunked swizzle
  const int shx = 31 - __clz(gridDim.x);      // gridDim.x is pow2 (16 or 4)
  const int bx = lin & (gridDim.x - 1), by = lin >> shx;
  const int quad = lane >> 4, rit = lane & 15;
  const int Mrows = gridDim.y * (MT * 16);
  const size_t psA = (size_t)Mrows * K * 2;
  const size_t psB = (size_t)N * K * 2;
  const int KB = K >> 5;
  const int wm = (w >> 1) * (MT / 2), wn = (w & 1) * 4;

  auto STAGE = [&](char* buf, int kt) {
    char* bufA = buf;
    char* bufB = buf + MT * 2 * 1024;
#pragma unroll
    for (int r = 0; r < MT / 2; r++) {
      int q = w + 4 * r;
      int p = q / MT, tt = q % MT;
      async16(bufA + (p * MT + tt) * 1024,
              AP + p * psA + ((size_t)(by * MT + tt) * KB + kt) * 1024 + lane * 16);
    }
#pragma unroll
    for (int r = 0; r < 4; r++) {
      int q = w + 4 * r;
      int p = q >> 3, tt = q & 7;
      async16(bufB + (p * 8 + tt) * 1024,
              BP + p * psB + ((size_t)(bx * 8 + tt) * KB + kt) * 1024 + lane * 16);
    }
  };

  f32x4 acc[MT / 2][4];
#pragma unroll
  for (int i = 0; i < MT / 2; i++)
#pragma unroll
    for (int j = 0; j < 4; j++) acc[i][j] = (f32x4){0.f, 0.f, 0.f, 0.f};

  // prologue: stage kt = 0..DEPTH-1; wait own-wave oldest batch (kt=0)
#pragma unroll
  for (int d = 0; d < DEPTH; d++) STAGE(lds + d * (NT * 1024), d);
  if constexpr (DEPTH == 3) asm volatile("s_waitcnt vmcnt(12)" ::: "memory");
  else if constexpr (MT == 8) asm volatile("s_waitcnt vmcnt(8)" ::: "memory");
  else asm volatile("s_waitcnt vmcnt(6)" ::: "memory");
  __builtin_amdgcn_s_barrier();
  __builtin_amdgcn_sched_barrier(0);

  int cur = 0;
  for (int kt = 0; kt < KB; kt++) {
    char* cb = lds + cur * (NT * 1024);
    cur = (cur + 1 == DEPTH) ? 0 : cur + 1;
    short8 af[2][MT / 2], bf[2][4];
#pragma unroll
    for (int p = 0; p < 2; p++)
#pragma unroll
      for (int mi = 0; mi < MT / 2; mi++)
        af[p][mi] = *(const short8*)(cb + (p * MT + wm + mi) * 1024 + lane * 16);
#pragma unroll
    for (int ni = 0; ni < 4; ni++) {
      const char* bb = cb + MT * 2 * 1024 + (wn + ni) * 1024 + lane * 16;
      bf[0][ni] = *(const short8*)(bb);
      bf[1][ni] = *(const short8*)(bb + 8192);
    }
    asm volatile("s_waitcnt lgkmcnt(0)" ::: "memory");
    __builtin_amdgcn_sched_barrier(0);
    __builtin_amdgcn_s_barrier();          // all waves done reading cb
    if (kt + DEPTH < KB) STAGE(cb, kt + DEPTH);  // overwrite cb
    __builtin_amdgcn_s_setprio(1);
#pragma unroll
    for (int ni = 0; ni < 4; ni++)
#pragma unroll
      for (int mi = 0; mi < MT / 2; mi++) {
        f32x4 c = acc[mi][ni];
        c = __builtin_amdgcn_mfma_f32_16x16x32_bf16(af[0][mi], bf[0][ni], c, 0, 0, 0);
        c = __builtin_amdgcn_mfma_f32_16x16x32_bf16(af[0][mi], bf[1][ni], c, 0, 0, 0);
        c = __builtin_amdgcn_mfma_f32_16x16x32_bf16(af[1][mi], bf[0][ni], c, 0, 0, 0);
        acc[mi][ni] = c;
      }
    __builtin_amdgcn_s_setprio(0);
    // wait until kt+1's stage complete; later stages remain in flight
    if constexpr (DEPTH == 3) {
      if (kt + 3 < KB)      asm volatile("s_waitcnt vmcnt(12)" ::: "memory");
      else if (kt + 2 < KB) asm volatile("s_waitcnt vmcnt(6)" ::: "memory");
      else                  asm volatile("s_waitcnt vmcnt(0)" ::: "memory");
    } else {
      if (kt + 2 < KB) {
        if constexpr (MT == 8) asm volatile("s_waitcnt vmcnt(8)" ::: "memory");
        else                   asm volatile("s_waitcnt vmcnt(6)" ::: "memory");
      } else {
        asm volatile("s_waitcnt vmcnt(0)" ::: "memory");
      }
    }
    __builtin_amdgcn_s_barrier();          // buf[kt+1] ready for all waves
    __builtin_amdgcn_sched_barrier(0);
  }

  const int n0 = bx * 128, m_base = by * (MT * 16);
  if (!PLANES_OUT) {
    float* C = (float*)Cout;
#pragma unroll
    for (int mi = 0; mi < MT / 2; mi++) {
      const int gr0 = m_base + (wm + mi) * 16 + quad * 4;
#pragma unroll
      for (int ni = 0; ni < 4; ni++) {
        const int gc = n0 + (wn + ni) * 16 + rit;
        const float bia = bias[gc];
#pragma unroll
        for (int e = 0; e < 4; e++) {
          float v = acc[mi][ni][e] + bia;
          if (GELU) v = 0.5f * v * (1.0f + erff(v * 0.7071067811865476f));
          C[(size_t)(gr0 + e) * N + gc] = v;
        }
      }
    }
  } else {
    // write gelu output as frag-order planes (M = Mrows, "K" = N)
    char* CP = (char*)Cout;
    const size_t psC = (size_t)Mrows * N * 2;
    float* lf = (float*)lds;   // 128 x 64 fp32 = 32 KB scratch
    for (int h = 0; h < 2; h++) {
      __syncthreads();
      if ((w & 1) == h) {
#pragma unroll
        for (int ni = 0; ni < 4; ni++) {
          const float bia = bias[n0 + h * 64 + ni * 16 + rit];
#pragma unroll
          for (int mi = 0; mi < MT / 2; mi++) {
            const int ml0 = (wm + mi) * 16 + quad * 4;
#pragma unroll
            for (int e = 0; e < 4; e++) {
              float v = acc[mi][ni][e] + bia;
              if (GELU) v = 0.5f * v * (1.0f + erff(v * 0.7071067811865476f));
              lf[(ml0 + e) * 64 + ni * 16 + rit] = v;
            }
          }
        }
      }
      __syncthreads();
#pragma unroll
      for (int it = 0; it < (MT * 16 * 8) / 256; it++) {
        int p = it * 256 + t;
        int ml = p >> 3, n8 = p & 7;
        float4 v0 = *(const float4*)&lf[ml * 64 + n8 * 8];
        float4 v1 = *(const float4*)&lf[ml * 64 + n8 * 8 + 4];
        uint4 H, Md;
        split2u(v0, v1, H, Md);
        int mg = m_base + ml, kg = n0 + h * 64 + n8 * 8;
        size_t off = ((size_t)(mg >> 4) * (N >> 5) + (kg >> 5)) * 1024
                   + (size_t)(((kg >> 3) & 3) * 256 + (mg & 15) * 16);
        *(uint4*)(CP + off) = H;
        *(uint4*)(CP + psC + off) = Md;
      }
    }
  }
}

extern "C" void kernel_launch(void* const* d_in, const int* in_sizes, int n_in,
                              void* d_out, int out_size, void* d_ws, size_t ws_size,
                              hipStream_t stream) {
  const float* x     = (const float*)d_in[0];
  const float* emb_w = (const float*)d_in[1];
  const float* emb_b = (const float*)d_in[2];
  const float* ln1_s = (const float*)d_in[3];
  const float* ln1_b = (const float*)d_in[4];
  const float* w1    = (const float*)d_in[5];
  const float* b1    = (const float*)d_in[6];
  const float* w2    = (const float*)d_in[7];
  const float* b2    = (const float*)d_in[8];
  const float* ln2_s = (const float*)d_in[9];
  const float* ln2_b = (const float*)d_in[10];
  const float* out_w = (const float*)d_in[11];
  const float* out_b = (const float*)d_in[12];
  float* outp = (float*)d_out;

  char* ws = (char*)d_ws;
  if (ws_size < (212ULL << 20)) return;
  float* PE    = (float*)(ws);                    // 8 MiB, dead after embed
  char*  W1S   = ws;                              // 4 MiB planes, overlay PE
  float* BUF[3] = { (float*)(ws + (8ULL << 20)),
                    (float*)(ws + (72ULL << 20)),
                    (float*)(ws + (136ULL << 20)) };  // 3 x 64 MiB
  char*  W2S   = ws + (200ULL << 20);             // 4 MiB planes
  float* MB    = (float*)(ws + (206ULL << 20));   // 1 MiB
  int*   IDX   = (int*)  (ws + (207ULL << 20));
  int*   TOP   = (int*)  (ws + (208ULL << 20));
  float* MEANQ = (float*)(ws + (208ULL << 20) + (64 << 10));
  double* PART = (double*)(ws + (209ULL << 20));  // 1 MiB (64*32*64 fp64)
  char*  FLG   = ws + (210ULL << 20);             // 256 KiB (64 bh x L)
  float* CTX   = (float*)(ws + (210ULL << 20) + (512 << 10));   // 768 KiB

  k_pe<<<256, 256, 0, stream>>>(PE);
  k_embed<<<(8 * 4096) / 16, 256, 0, stream>>>(x, emb_w, emb_b, PE, BUF[0]);

  const int Ls[3] = {4096, 2048, 1024};
  const int Lshs[3] = {12, 11, 10};
  const int us[3] = {45, 40, 35};
  int xi = 0, ai = 1, yi = 2;
  char* FINALP = nullptr;
  for (int layer = 0; layer < 3; layer++) {
    const int L = Ls[layer], u = us[layer];
    float* X = BUF[xi]; float* A = BUF[ai]; float* Y = BUF[yi];

    // per-layer weight planes (PE dead after embed)
    k_splitX<<<(2048 * 512 / 8) / 256, 256, 0, stream>>>(
        w1 + (size_t)layer * 2048 * 512, W1S, 512, 2048 * 512 / 8);
    k_splitX<<<(512 * 2048 / 8) / 256, 256, 0, stream>>>(
        w2 + (size_t)layer * 512 * 2048, W2S, 2048, 512 * 2048 / 8);

    unsigned Ka, Kb, k2a, k2b;
    tf2x32(0u, 42u, 0u, (unsigned)layer, Ka, Kb);
    tf2x32(Ka, Kb, 0u, 1u, k2a, k2b);
    const int n = L * u;
    k_idx<<<(n + 255) / 256, 256, 0, stream>>>(IDX, k2a, k2b, n, L - 1);
    const int S = 32;
    k_colmean1<<<dim3(S, 64), 256, 0, stream>>>(X, PART, L, S);
    k_colmean2<<<64, 64, 0, stream>>>(PART, MEANQ, L, S);
    k_M<<<64 * L / 4, 256, 0, stream>>>(X, IDX, MB, L, Lshs[layer], u,
                                        1.0f / (float)L);
    k_topk<<<64, 256, 0, stream>>>(MB, TOP, L, u);
    hipMemsetAsync(FLG, 0, (size_t)64 * L, stream);
    // S (scores) lives at Y [<48 MiB]; PV partials + stats in Y's tail
    float* P2 = (float*)((char*)Y + (48ULL << 20));   // 6.3 MiB
    float* MS = (float*)((char*)Y + (56ULL << 20));   // 98 KiB
    float* SS = (float*)((char*)Y + (57ULL << 20));   // 98 KiB
    k_scores<<<dim3(L / 64, 64), 256, 0, stream>>>(X, TOP, Y, L, u);
    k_pv<<<dim3(PVSEG, 64), 256, 0, stream>>>(X, Y, P2, MS, SS, L, u);
    k_pvred<<<64, 256, 0, stream>>>(P2, MS, SS, TOP, CTX, FLG, L, u);
    // LN1 in-place + X-planes for ALL chunks directly into A (dead region)
    k_ln1<<<8 * L / 4, 256, 0, stream>>>(X, FLG, CTX, MEANQ,
                                         ln1_s + layer * 512,
                                         ln1_b + layer * 512, (char*)A,
                                         L, Lshs[layer]);

    // FFN in 8192-row super-chunks. YP planes (64 MiB) fill Y entirely.
    // XP[c] pre-written by k_ln1 inside A[c]; gemm2 overwrites A[c] after
    // gemm1[c] consumed it. Chunks are self-contained -> no cross clobber.
    char* YP = (char*)Y;
    const int chunks = (8 * L) / 8192;
    for (int c = 0; c < chunks; c++) {
      float* Ac = A + (size_t)c * 8192 * 512;
      char* XP = (char*)Ac;
      k_gemm6<8, 1, 1, 2><<<dim3(16, 64), 256, 0, stream>>>(
          XP, W1S, b1 + layer * 2048, YP, 2048, 512);
      k_gemm6<4, 0, 0, 3><<<dim3(4, 128), 256, 0, stream>>>(
          YP, W2S, b2 + layer * 512, Ac, 512, 2048);
    }
    if (layer < 2) {
      k_ln2<<<8 * (L / 2) / 4, 256, 0, stream>>>(X, A, ln2_s + layer * 512,
                                                 ln2_b + layer * 512, Y);
    } else {
      // final LN emits planes straight into Y (16 MiB) for the projection
      FINALP = (char*)Y;
      k_ln2p<<<8 * L / 4, 256, 0, stream>>>(X, A, ln2_s + layer * 512,
                                            ln2_b + layer * 512, FINALP);
    }
    int tswap = xi; xi = yi; yi = ai; ai = tswap;  // next X = Y
  }
  // final projection: (8192, 512) @ out_w^T + out_b, planes from k_ln2p
  char* WOS = W2S;                                 // 1 MiB planes
  k_splitX<<<(512 * 512 / 8) / 256, 256, 0, stream>>>(out_w, WOS, 512, 512 * 512 / 8);
  k_gemm6<4, 0, 0, 3><<<dim3(4, 128), 256, 0, stream>>>(
      FINALP, WOS, out_b, outp, 512, 512);
}

// Round 15
// 2004.268 us; speedup vs baseline: 1.0388x; 1.0388x over previous
//
#include <hip/hip_runtime.h>
#include <hip/hip_bf16.h>
#include <math.h>

// ---- JAX threefry RNG: partitionable, bits = o0 ^ o1 [VERIFIED round 2] ----

typedef short short8 __attribute__((ext_vector_type(8)));
typedef float f32x4 __attribute__((ext_vector_type(4)));
typedef unsigned int uint;

__host__ __device__ inline void tf2x32(unsigned k0, unsigned k1,
                                       unsigned x0, unsigned x1,
                                       unsigned& o0, unsigned& o1) {
  unsigned ks2 = k0 ^ k1 ^ 0x1BD11BDAu;
#define TF_R(x, r) x0 += x1; x1 = ((x1 << (r)) | (x1 >> (32 - (r)))); x1 ^= x0;
  x0 += k0; x1 += k1;
  TF_R(x1,13) TF_R(x1,15) TF_R(x1,26) TF_R(x1,6)
  x0 += k1; x1 += ks2 + 1u;
  TF_R(x1,17) TF_R(x1,29) TF_R(x1,16) TF_R(x1,24)
  x0 += ks2; x1 += k0 + 2u;
  TF_R(x1,13) TF_R(x1,15) TF_R(x1,26) TF_R(x1,6)
  x0 += k0; x1 += k1 + 3u;
  TF_R(x1,17) TF_R(x1,29) TF_R(x1,16) TF_R(x1,24)
  x0 += k1; x1 += ks2 + 4u;
  TF_R(x1,13) TF_R(x1,15) TF_R(x1,26) TF_R(x1,6)
  x0 += ks2; x1 += k0 + 5u;
#undef TF_R
  o0 = x0; o1 = x1;
}

// ---------------- bf16x2 plane machinery ----------------
// fp32 matrix [M][K] row-major -> 2 bf16 planes (hi/mid) in MFMA
// fragment-tile order: plane[tile16_m][kblock32][lane64][8 bf16], where
// lane = ((k>>3)&3)*16 + (m&15), j = k&7.  Tile = 1024 B contiguous.
// 3-term product (hh, hm, mh): dropped terms ~5e-6 abs << 0.0078 slack.

__device__ inline unsigned bsplit(float x, float y, float& rx, float& ry) {
  union { __hip_bfloat162 h; unsigned u; } c;
  c.h = __float22bfloat162_rn(make_float2(x, y));
  rx = x - __uint_as_float(c.u << 16);
  ry = y - __uint_as_float(c.u & 0xffff0000u);
  return c.u;
}

__device__ inline void split2u(float4 v0, float4 v1, uint4& H, uint4& M) {
  float r[8]; float d0, d1;
  H.x = bsplit(v0.x, v0.y, r[0], r[1]);
  H.y = bsplit(v0.z, v0.w, r[2], r[3]);
  H.z = bsplit(v1.x, v1.y, r[4], r[5]);
  H.w = bsplit(v1.z, v1.w, r[6], r[7]);
  M.x = bsplit(r[0], r[1], d0, d1);
  M.y = bsplit(r[2], r[3], d0, d1);
  M.z = bsplit(r[4], r[5], d0, d1);
  M.w = bsplit(r[6], r[7], d0, d1);
}

__global__ void k_idx(int* __restrict__ idx, unsigned k2a, unsigned k2b,
                      int n, int mask) {
  int j = blockIdx.x * 256 + threadIdx.x;
  if (j >= n) return;
  unsigned o0, o1;
  tf2x32(k2a, k2b, 0u, (unsigned)j, o0, o1);
  idx[j] = (int)((o0 ^ o1) & (unsigned)mask);
}

// positional-encoding table via fp64 rotation recurrence: thread owns one
// d-pair and a 16-row strip; 2 sincos + 16x4 f64 FMA replaces 16 sincos.
// Rotation error ~1e-14 << f32 table rounding -> matches fp64 path exactly.
__global__ __launch_bounds__(256) void k_pe(float* __restrict__ pe) {
  int d2 = threadIdx.x;            // 0..255 (d-pair)
  int l0 = blockIdx.x * 16;        // 256 blocks x 16 rows
  double th = exp((double)(2 * d2) * (-9.210340371976184 / 512.0));
  double sT = sin(th), cT = cos(th);
  double a = (double)l0 * th;
  double s = sin(a), c = cos(a);
  float* row = pe + (size_t)l0 * 512 + 2 * d2;
#pragma unroll
  for (int i = 0; i < 16; i++) {
    row[0] = (float)s; row[1] = (float)c;
    double ns = s * cT + c * sT;
    double nc = c * cT - s * sT;
    s = ns; c = nc;
    row += 512;
  }
}

// h = x @ emb_w^T + emb_b + pe   (K=64, 16 rows per block)
__global__ __launch_bounds__(256) void k_embed(const float* __restrict__ x,
    const float* __restrict__ W, const float* __restrict__ eb,
    const float* __restrict__ pe, float* __restrict__ out) {
  __shared__ __align__(16) float xs[16][64];
  int r0 = blockIdx.x * 16;
  int t = threadIdx.x;
  ((float4*)&xs[0][0])[t] = ((const float4*)(x + (size_t)r0 * 64))[t];
  __syncthreads();
  int d0 = t, d1 = t + 256;
  float acc0[16], acc1[16];
#pragma unroll
  for (int r = 0; r < 16; r++) { acc0[r] = 0.f; acc1[r] = 0.f; }
  for (int k = 0; k < 64; k++) {
    float w0 = W[d0 * 64 + k], w1 = W[d1 * 64 + k];
#pragma unroll
    for (int r = 0; r < 16; r++) {
      float xv = xs[r][k];
      acc0[r] = fmaf(xv, w0, acc0[r]);
      acc1[r] = fmaf(xv, w1, acc1[r]);
    }
  }
  float eb0 = eb[d0], eb1 = eb[d1];
#pragma unroll
  for (int r = 0; r < 16; r++) {
    int row = r0 + r;
    int l = row & 4095;
    out[(size_t)row * 512 + d0] = acc0[r] + eb0 + pe[(size_t)l * 512 + d0];
    out[(size_t)row * 512 + d1] = acc1[r] + eb1 + pe[(size_t)l * 512 + d1];
  }
}

// column-mean phase 1: per-(seg,bh) fp64 partial sums (grid saturates CUs)
__global__ __launch_bounds__(256) void k_colmean1(const float* __restrict__ X,
    double* __restrict__ part, int L, int S) {
  int seg = blockIdx.x, bh = blockIdx.y, b = bh >> 3, h = bh & 7;
  int w = threadIdx.x >> 6, d = threadIdx.x & 63;
  int rows = L / S, r0 = seg * rows;
  const float* base = X + (size_t)b * L * 512 + h * 64 + d;
  double s = 0.0;
  for (int l = r0 + w; l < r0 + rows; l += 4) s += (double)base[(size_t)l * 512];
  __shared__ double red[4][64];
  red[w][d] = s;
  __syncthreads();
  if (w == 0)
    part[((size_t)bh * S + seg) * 64 + d] =
        red[0][d] + red[1][d] + red[2][d] + red[3][d];
}

// column-mean phase 2: reduce S segments, divide by L
__global__ void k_colmean2(const double* __restrict__ part,
    float* __restrict__ meanq, int L, int S) {
  int bh = blockIdx.x, d = threadIdx.x;
  const double* p = part + (size_t)bh * S * 64 + d;
  double s = 0.0;
  for (int seg = 0; seg < S; seg++) s += p[seg * 64];
  meanq[bh * 64 + d] = (float)(s / (double)L);
}

// M[b,h,l] = max_s dot(q_l,k_s) - sum_s(...)/L.  Pure f32 (round-2 numerics).
// ROUND-6 VARIANT (best measured: 155us, occ 83%): 4 lanes per gathered row,
// 12 gathers issued up-front for ILP, barrier after qs staging.
__global__ __launch_bounds__(256) void k_M(const float* __restrict__ X,
    const int* __restrict__ idx, float* __restrict__ Mout, int L, int Lsh,
    int u, float invL) {
  int w = threadIdx.x >> 6, lane = threadIdx.x & 63;
  int gl = blockIdx.x * 4 + w;
  int l = gl & (L - 1), bh = gl >> Lsh, b = bh >> 3, h = bh & 7;
  const float* Xbh = X + (size_t)b * L * 512 + h * 64;
  __shared__ float qs[4][64];
  qs[w][lane] = Xbh[(size_t)l * 512 + lane];
  __syncthreads();
  const int s16 = lane >> 2, j = lane & 3;
  float4 qv[4];
#pragma unroll
  for (int c = 0; c < 4; c++) qv[c] = *(const float4*)&qs[w][c * 16 + j * 4];
  const int base = l * u;
  int kx[3];
#pragma unroll
  for (int g = 0; g < 3; g++) {
    int s = g * 16 + s16;
    kx[g] = (s < u) ? idx[base + s] : 0;
  }
  float4 kv[3][4];
#pragma unroll
  for (int g = 0; g < 3; g++) {
    const float* row = Xbh + (size_t)kx[g] * 512 + j * 4;
#pragma unroll
    for (int c = 0; c < 4; c++) kv[g][c] = *(const float4*)(row + c * 16);
  }
  float mv = -1e30f, sv = 0.f;
#pragma unroll
  for (int g = 0; g < 3; g++) {
    float pc[4];
#pragma unroll
    for (int c = 0; c < 4; c++) {
      float p = qv[c].x * kv[g][c].x;
      p = fmaf(qv[c].y, kv[g][c].y, p);
      p = fmaf(qv[c].z, kv[g][c].z, p);
      p = fmaf(qv[c].w, kv[g][c].w, p);
      pc[c] = p;
    }
    float d = (pc[0] + pc[1]) + (pc[2] + pc[3]);
    d += __shfl_xor(d, 1);
    d += __shfl_xor(d, 2);          // all 4 j-lanes now hold dot_s
    if (g * 16 + s16 < u) { mv = fmaxf(mv, d); sv += d; }
  }
  for (int off = 4; off < 64; off <<= 1) {
    mv = fmaxf(mv, __shfl_xor(mv, off));
    sv += __shfl_xor(sv, off);
  }
  if (lane == 0) Mout[(size_t)bh * L + l] = mv - sv * invL;
}

// iterative top-u argmax per (b,h); tie -> smaller index (matches lax.top_k).
// Cached per-thread local max; only the winner's owner rescans its strided
// chunk. Wave shfl tree + 2 barriers/iter.
__global__ __launch_bounds__(256) void k_topk(const float* __restrict__ M,
    int* __restrict__ top, int L, int u) {
  __shared__ float mv[4096];
  __shared__ float wv[4];
  __shared__ int wi[4];
  __shared__ int bi_s;
  int bh = blockIdx.x, t = threadIdx.x;
  int w = t >> 6, lane = t & 63;
  const float* Mr = M + (size_t)bh * L;
  for (int k = t; k < L; k += 256) mv[k] = Mr[k];
  __syncthreads();
  float lv = -1e30f; int li = 0x7fffffff;
  for (int k = t; k < L; k += 256) {
    float v = mv[k];
    if (v > lv) { lv = v; li = k; }   // ascending k -> earliest on ties
  }
  for (int it = 0; it < u; it++) {
    float v = lv; int i = li;
#pragma unroll
    for (int off = 1; off < 64; off <<= 1) {
      float v2 = __shfl_xor(v, off); int i2 = __shfl_xor(i, off);
      if (v2 > v || (v2 == v && i2 < i)) { v = v2; i = i2; }
    }
    if (lane == 0) { wv[w] = v; wi[w] = i; }
    __syncthreads();
    if (t == 0) {
      float bv = wv[0]; int bi = wi[0];
#pragma unroll
      for (int jj = 1; jj < 4; jj++) {
        if (wv[jj] > bv || (wv[jj] == bv && wi[jj] < bi)) { bv = wv[jj]; bi = wi[jj]; }
      }
      top[bh * u + it] = bi;
      mv[bi] = -1e30f;
      bi_s = bi;
    }
    __syncthreads();
    int bi = bi_s;
    if ((bi & 255) == t) {            // owner refreshes its cached local max
      lv = -1e30f; li = 0x7fffffff;
      for (int k = t; k < L; k += 256) {
        float v = mv[k];
        if (v > lv) { lv = v; li = k; }
      }
    }
  }
}

// S[bh,ur,k] = scale * dot(q_red[ur], q_k) for 64-k tile per block
__global__ __launch_bounds__(256) void k_scores(const float* __restrict__ X,
    const int* __restrict__ top, float* __restrict__ S, int L, int u) {
  __shared__ __align__(16) float ktT[64][68];
  __shared__ __align__(16) float qred[48][64];
  int bh = blockIdx.y, b = bh >> 3, h = bh & 7;
  int k0 = blockIdx.x * 64;
  int t = threadIdx.x;
  const float* Xbh = X + (size_t)b * L * 512 + h * 64;
#pragma unroll
  for (int it = 0; it < 4; it++) {
    int lin = t + it * 256;                // (kk, fi) over 64x16
    int kk = lin >> 4, fi = lin & 15;
    float4 v = *(const float4*)(Xbh + (size_t)(k0 + kk) * 512 + fi * 4);
    ktT[fi * 4 + 0][kk] = v.x; ktT[fi * 4 + 1][kk] = v.y;
    ktT[fi * 4 + 2][kk] = v.z; ktT[fi * 4 + 3][kk] = v.w;
  }
#pragma unroll
  for (int it = 0; it < 3; it++) {
    int lin = t + it * 256;                // (ur, fi) over 48x16
    int ur = lin >> 4, fi = lin & 15;
    if (ur < u) {
      int row = top[bh * u + ur];
      *(float4*)(&qred[ur][fi * 4]) = *(const float4*)(Xbh + (size_t)row * 512 + fi * 4);
    } else if (ur < 48) {
      *(float4*)(&qred[ur][fi * 4]) = make_float4(0.f, 0.f, 0.f, 0.f);
    }
  }
  __syncthreads();
  int xq = t & 15, y = t >> 4;
  float acc[3][4];
#pragma unroll
  for (int j = 0; j < 3; j++)
#pragma unroll
    for (int e = 0; e < 4; e++) acc[j][e] = 0.f;
  for (int d = 0; d < 64; d++) {
    float4 kv = *(const float4*)(&ktT[d][xq * 4]);
#pragma unroll
    for (int j = 0; j < 3; j++) {
      float qv = qred[y * 3 + j][d];
      acc[j][0] = fmaf(qv, kv.x, acc[j][0]);
      acc[j][1] = fmaf(qv, kv.y, acc[j][1]);
      acc[j][2] = fmaf(qv, kv.z, acc[j][2]);
      acc[j][3] = fmaf(qv, kv.w, acc[j][3]);
    }
  }
#pragma unroll
  for (int j = 0; j < 3; j++) {
    int ur = y * 3 + j;
    if (ur < u) {
      float4 o = make_float4(acc[j][0] * 0.125f, acc[j][1] * 0.125f,
                             acc[j][2] * 0.125f, acc[j][3] * 0.125f);
      *(float4*)(S + ((size_t)(bh * u + ur)) * L + k0 + xq * 4) = o;
    }
  }
}

// PV partials, flash-style: block=(seg,bh) computes per-ur SEGMENT-local max
// (pre-pass over its own S slice; slice then L2-hot for the weight pass),
// accumulates acc = sum_l exp(s - m_seg) * x  and  esum = sum_l exp(s - m_seg).
// k_pvred combines segments with exp(m_seg - mx) factors (max of seg-maxes
// == global max exactly).
#define PVSEG 8
__global__ __launch_bounds__(256) void k_pv(const float* __restrict__ X,
    const float* __restrict__ S, float* __restrict__ P2,
    float* __restrict__ MS, float* __restrict__ SS, int L, int u) {
  __shared__ __align__(16) float xs[32][64];
  __shared__ __align__(16) float wsm[32][52];   // pad 48->52 (bank spread)
  int seg = blockIdx.x, bh = blockIdx.y, b = bh >> 3, h = bh & 7;
  int t = threadIdx.x, w = t >> 6, lane = t & 63;
  int rows = L / PVSEG, l0 = seg * rows;
  const float* Xb = X + (size_t)b * L * 512 + h * 64;
  int li = lane & 31, par = lane >> 5;
  const float* Sp[6]; int val[6];
#pragma unroll
  for (int jj = 0; jj < 6; jj++) {
    int ur = w * 12 + par + jj * 2;
    val[jj] = (ur < u);
    Sp[jj] = S + (size_t)(bh * u + (val[jj] ? ur : 0)) * L + l0 + li;
  }
  // pass 1: segment-local max per ur (32 li-lanes cover rows); doubles as
  // L2 prefetch of this block's S slice for the weight pass below.
  float mloc[6];
#pragma unroll
  for (int jj = 0; jj < 6; jj++) mloc[jj] = -1e30f;
  for (int c = 0; c < rows; c += 32) {
#pragma unroll
    for (int jj = 0; jj < 6; jj++) mloc[jj] = fmaxf(mloc[jj], Sp[jj][c]);
  }
#pragma unroll
  for (int jj = 0; jj < 6; jj++) {
#pragma unroll
    for (int off = 1; off < 32; off <<= 1)
      mloc[jj] = fmaxf(mloc[jj], __shfl_xor(mloc[jj], off));
  }
  float acc[12], esum[6];
#pragma unroll
  for (int j = 0; j < 12; j++) acc[j] = 0.f;
#pragma unroll
  for (int j = 0; j < 6; j++) esum[j] = 0.f;
  int xr = t >> 4, xf = t & 15;
  for (int c = 0; c < rows; c += 32) {
    __syncthreads();
    *(float4*)&xs[xr][xf * 4] =
        *(const float4*)(Xb + (size_t)(l0 + c + xr) * 512 + xf * 4);
    *(float4*)&xs[16 + xr][xf * 4] =
        *(const float4*)(Xb + (size_t)(l0 + c + 16 + xr) * 512 + xf * 4);
#pragma unroll
    for (int jj = 0; jj < 6; jj++) {
      float e = val[jj] ? expf(Sp[jj][c] - mloc[jj]) : 0.f;
      esum[jj] += e;
      wsm[li][w * 12 + par + jj * 2] = e;
    }
    __syncthreads();
#pragma unroll 2
    for (int l = 0; l < 32; l++) {
      float xv = xs[l][lane];
      float4 w0 = *(const float4*)&wsm[l][w * 12];
      float4 w1 = *(const float4*)&wsm[l][w * 12 + 4];
      float4 w2 = *(const float4*)&wsm[l][w * 12 + 8];
      acc[0]  = fmaf(w0.x, xv, acc[0]);  acc[1]  = fmaf(w0.y, xv, acc[1]);
      acc[2]  = fmaf(w0.z, xv, acc[2]);  acc[3]  = fmaf(w0.w, xv, acc[3]);
      acc[4]  = fmaf(w1.x, xv, acc[4]);  acc[5]  = fmaf(w1.y, xv, acc[5]);
      acc[6]  = fmaf(w1.z, xv, acc[6]);  acc[7]  = fmaf(w1.w, xv, acc[7]);
      acc[8]  = fmaf(w2.x, xv, acc[8]);  acc[9]  = fmaf(w2.y, xv, acc[9]);
      acc[10] = fmaf(w2.z, xv, acc[10]); acc[11] = fmaf(w2.w, xv, acc[11]);
    }
  }
  float* P = P2 + ((size_t)(bh * PVSEG + seg) * 48 + w * 12) * 64 + lane;
#pragma unroll
  for (int j = 0; j < 12; j++) P[j * 64] = acc[j];
#pragma unroll
  for (int jj = 0; jj < 6; jj++) {
    float es = esum[jj];
#pragma unroll
    for (int off = 1; off < 32; off <<= 1) es += __shfl_xor(es, off);
    if (li == 0) {
      int ur = w * 12 + par + jj * 2;
      MS[((size_t)bh * PVSEG + seg) * 48 + ur] = mloc[jj];
      SS[((size_t)bh * PVSEG + seg) * 48 + ur] = es;
    }
  }
}

// combine segments: mx = max_seg m_seg; den = sum_seg esum_seg*exp(m_seg-mx);
// ctx = sum_seg acc_seg*exp(m_seg-mx) / den. Writes compact CTX + FLG=ur+1.
__global__ __launch_bounds__(256) void k_pvred(const float* __restrict__ P2,
    const float* __restrict__ MS, const float* __restrict__ SS,
    const int* __restrict__ top, float* __restrict__ CTX,
    char* __restrict__ FLG, int L, int u) {
  int bh = blockIdx.x;
  int t = threadIdx.x;
  const float* Pb = P2 + (size_t)bh * PVSEG * 48 * 64;
  const float* Mb = MS + (size_t)bh * PVSEG * 48;
  const float* Sb = SS + (size_t)bh * PVSEG * 48;
  __shared__ float fac[PVSEG][48];
  __shared__ double dens[48];
  if (t < u) {
    float mx = Mb[t];
#pragma unroll
    for (int s = 1; s < PVSEG; s++) mx = fmaxf(mx, Mb[s * 48 + t]);
    double den = 0.0;
#pragma unroll
    for (int s = 0; s < PVSEG; s++) {
      float f = expf(Mb[s * 48 + t] - mx);
      fac[s][t] = f;
      den += (double)Sb[s * 48 + t] * (double)f;
    }
    dens[t] = den;
  }
  __syncthreads();
  for (int e = t; e < u * 64; e += 256) {
    int ur = e >> 6, d = e & 63;
    const float* p = Pb + ur * 64 + d;
    const int st = 48 * 64;
    double num = 0.0;
#pragma unroll
    for (int s = 0; s < PVSEG; s++)
      num += (double)p[s * st] * (double)fac[s][ur];
    double tot = num / dens[ur];
    CTX[((size_t)bh * 48 + ur) * 64 + d] = (float)tot;
    if (d == 0) FLG[(size_t)bh * L + top[bh * u + ur]] = (char)(ur + 1);
  }
}

// X <- LN(X + ctx) * gs + gb, in place, AND emit bf16x2 planes of the result
// into the (dead) A region, chunk-local frag order (replaces k_splitX(X)).
// One wave per row; lane owns 8 consecutive cols (d = lane*8 + i), so each
// lane emits one H/Md uint4 pair. ctx from compact CTX via FLG (=ur+1).
__global__ __launch_bounds__(256) void k_ln1(float* __restrict__ X,
    const char* __restrict__ FLG, const float* __restrict__ CTX,
    const float* __restrict__ meanq, const float* __restrict__ gs,
    const float* __restrict__ gb, char* __restrict__ XPbase, int L, int Lsh) {
  int w = threadIdx.x >> 6, lane = threadIdx.x & 63;
  int row = blockIdx.x * 4 + w;
  int b = row >> Lsh, l = row & (L - 1);
  float* xr = X + (size_t)row * 512;
  int h = lane >> 3;                          // head of this lane's 8 cols
  int bh = b * 8 + h;
  int flag = (int)FLG[(size_t)bh * L + l];    // 0 or ur+1
  float4 c0, c1;
  if (flag) {
    const float* cx = CTX + ((size_t)bh * 48 + (flag - 1)) * 64 + (lane & 7) * 8;
    c0 = *(const float4*)cx; c1 = *(const float4*)(cx + 4);
  } else {
    const float* mq = meanq + b * 512 + lane * 8;
    c0 = *(const float4*)mq; c1 = *(const float4*)(mq + 4);
  }
  float4 x0 = *(const float4*)(xr + lane * 8);
  float4 x1 = *(const float4*)(xr + lane * 8 + 4);
  float v[8] = { x0.x + c0.x, x0.y + c0.y, x0.z + c0.z, x0.w + c0.w,
                 x1.x + c1.x, x1.y + c1.y, x1.z + c1.z, x1.w + c1.w };
  double s = 0.0, s2 = 0.0;
#pragma unroll
  for (int i = 0; i < 8; i++) { s += (double)v[i]; s2 += (double)v[i] * (double)v[i]; }
  for (int off = 32; off; off >>= 1) { s += __shfl_xor(s, off); s2 += __shfl_xor(s2, off); }
  double mu = s * (1.0 / 512.0);
  double var = s2 * (1.0 / 512.0) - mu * mu;
  float rsd = (float)(1.0 / sqrt(var + 1e-5));
  float muf = (float)mu;
  float4 g0 = *(const float4*)(gs + lane * 8);
  float4 g1 = *(const float4*)(gs + lane * 8 + 4);
  float4 b0 = *(const float4*)(gb + lane * 8);
  float4 b1 = *(const float4*)(gb + lane * 8 + 4);
  float4 y0 = make_float4((v[0] - muf) * rsd * g0.x + b0.x,
                          (v[1] - muf) * rsd * g0.y + b0.y,
                          (v[2] - muf) * rsd * g0.z + b0.z,
                          (v[3] - muf) * rsd * g0.w + b0.w);
  float4 y1 = make_float4((v[4] - muf) * rsd * g1.x + b1.x,
                          (v[5] - muf) * rsd * g1.y + b1.y,
                          (v[6] - muf) * rsd * g1.z + b1.z,
                          (v[7] - muf) * rsd * g1.w + b1.w);
  *(float4*)(xr + lane * 8) = y0;
  *(float4*)(xr + lane * 8 + 4) = y1;
  // planes, chunk-local (8192-row chunks inside A region)
  int c = row >> 13, ml = row & 8191;
  char* P = XPbase + ((size_t)c << 24);       // 16 MiB per chunk
  const size_t psz = (size_t)8192 * 512 * 2;  // 8 MiB per plane
  int k = lane * 8;
  size_t off = ((size_t)(ml >> 4) * 16 + (k >> 5)) * 1024
             + (size_t)(((k >> 3) & 3) * 256 + (ml & 15) * 16);
  uint4 H, Md;
  split2u(y0, y1, H, Md);
  *(uint4*)(P + off) = H;
  *(uint4*)(P + psz + off) = Md;
}

// out <- LN(X + Y2) with pair-pool (distil); one wave per output row
__global__ __launch_bounds__(256) void k_ln2(const float* __restrict__ X,
    const float* __restrict__ Y2, const float* __restrict__ gs,
    const float* __restrict__ gb, float* __restrict__ out) {
  int w = threadIdx.x >> 6, lane = threadIdx.x & 63;
  int orow = blockIdx.x * 4 + w;
  float o[8] = {0.f,0.f,0.f,0.f,0.f,0.f,0.f,0.f};
  for (int p = 0; p < 2; p++) {
    int row = orow * 2 + p;
    const float* xr = X + (size_t)row * 512;
    const float* yr = Y2 + (size_t)row * 512;
    float v[8]; double s = 0.0, s2 = 0.0;
#pragma unroll
    for (int i = 0; i < 8; i++) {
      float val = xr[lane + i * 64] + yr[lane + i * 64];
      v[i] = val; s += (double)val; s2 += (double)val * (double)val;
    }
    for (int off = 32; off; off >>= 1) { s += __shfl_xor(s, off); s2 += __shfl_xor(s2, off); }
    double mu = s * (1.0 / 512.0);
    double var = s2 * (1.0 / 512.0) - mu * mu;
    float rsd = (float)(1.0 / sqrt(var + 1e-5));
    float muf = (float)mu;
#pragma unroll
    for (int i = 0; i < 8; i++)
      o[i] += (v[i] - muf) * rsd * gs[lane + i * 64] + gb[lane + i * 64];
  }
#pragma unroll
  for (int i = 0; i < 8; i++)
    out[(size_t)orow * 512 + lane + i * 64] = o[i] * 0.5f;
}

// final LN (no pool) emitting bf16x2 planes directly (M = 8192, K = 512);
// lane owns 8 consecutive cols. Replaces fp32 store + k_splitX.
__global__ __launch_bounds__(256) void k_ln2p(const float* __restrict__ X,
    const float* __restrict__ Y2, const float* __restrict__ gs,
    const float* __restrict__ gb, char* __restrict__ P) {
  int w = threadIdx.x >> 6, lane = threadIdx.x & 63;
  int row = blockIdx.x * 4 + w;
  const float* xr = X + (size_t)row * 512;
  const float* yr = Y2 + (size_t)row * 512;
  float4 x0 = *(const float4*)(xr + lane * 8);
  float4 x1 = *(const float4*)(xr + lane * 8 + 4);
  float4 z0 = *(const float4*)(yr + lane * 8);
  float4 z1 = *(const float4*)(yr + lane * 8 + 4);
  float v[8] = { x0.x + z0.x, x0.y + z0.y, x0.z + z0.z, x0.w + z0.w,
                 x1.x + z1.x, x1.y + z1.y, x1.z + z1.z, x1.w + z1.w };
  double s = 0.0, s2 = 0.0;
#pragma unroll
  for (int i = 0; i < 8; i++) { s += (double)v[i]; s2 += (double)v[i] * (double)v[i]; }
  for (int off = 32; off; off >>= 1) { s += __shfl_xor(s, off); s2 += __shfl_xor(s2, off); }
  double mu = s * (1.0 / 512.0);
  double var = s2 * (1.0 / 512.0) - mu * mu;
  float rsd = (float)(1.0 / sqrt(var + 1e-5));
  float muf = (float)mu;
  float4 g0 = *(const float4*)(gs + lane * 8);
  float4 g1 = *(const float4*)(gs + lane * 8 + 4);
  float4 b0 = *(const float4*)(gb + lane * 8);
  float4 b1 = *(const float4*)(gb + lane * 8 + 4);
  float4 y0 = make_float4((v[0] - muf) * rsd * g0.x + b0.x,
                          (v[1] - muf) * rsd * g0.y + b0.y,
                          (v[2] - muf) * rsd * g0.z + b0.z,
                          (v[3] - muf) * rsd * g0.w + b0.w);
  float4 y1 = make_float4((v[4] - muf) * rsd * g1.x + b1.x,
                          (v[5] - muf) * rsd * g1.y + b1.y,
                          (v[6] - muf) * rsd * g1.z + b1.z,
                          (v[7] - muf) * rsd * g1.w + b1.w);
  const size_t psz = (size_t)8192 * 512 * 2;
  int k = lane * 8;
  size_t off = ((size_t)(row >> 4) * 16 + (k >> 5)) * 1024
             + (size_t)(((k >> 3) & 3) * 256 + (row & 15) * 16);
  uint4 H, Md;
  split2u(y0, y1, H, Md);
  *(uint4*)(P + off) = H;
  *(uint4*)(P + psz + off) = Md;
}

// split fp32 [M][K] -> 2 planes frag-tile order. total8 = M*K/8. (weights)
__global__ void k_splitX(const float* __restrict__ X, char* __restrict__ P,
                         int K, int total8) {
  int f = blockIdx.x * 256 + threadIdx.x;
  if (f >= total8) return;
  int k8 = f % (K >> 3), m = f / (K >> 3);
  int k = k8 * 8;
  const float* src = X + (size_t)m * K + k;
  float4 v0 = *(const float4*)(src);
  float4 v1 = *(const float4*)(src + 4);
  uint4 H, Md;
  split2u(v0, v1, H, Md);
  size_t psz = (size_t)total8 * 16;   // M*K*2 bytes per plane
  size_t off = ((size_t)(m >> 4) * (K >> 5) + (k >> 5)) * 1024
             + (size_t)(((k >> 3) & 3) * 256 + (m & 15) * 16);
  *(uint4*)(P + off) = H;
  *(uint4*)(P + psz + off) = Md;
}

__device__ __forceinline__ void async16(void* lds, const void* g) {
  __builtin_amdgcn_global_load_lds(
      (const __attribute__((address_space(1))) uint*)g,
      (__attribute__((address_space(3))) uint*)lds, 16, 0, 0);
}

// C = A @ B^T + bias, A/B as bf16x2 frag-order planes. 3-term bf16x2
// (hh, hm, mh). Block tile: (MT*16) x 128, BK=32. 4 waves as 2x2.
// COUNTED-VMCNT 2-DEEP PIPELINE (T3/T4, round-12 proven config): double
// LDS buffers, raw s_barrier + inline-asm counted vmcnt so the next-next
// tile's global_load_lds stays in flight across barriers. DEPTH=2 + 3
// blocks/CU (MT=4) beat DEPTH=3 + 2 blocks/CU (round-13 A/B) -- occupancy
// outweighs in-block pipeline depth at this tile shape. Math identical to
// the plain loop (same MFMA order) -> bit-identical C.
// XCD-aware chunked swizzle (T1). PLANES_OUT epilogue unchanged.
template <int MT, int GELU, int PLANES_OUT>
__global__ __launch_bounds__(256) void k_gemm6(const char* __restrict__ AP,
    const char* __restrict__ BP, const float* __restrict__ bias,
    void* __restrict__ Cout, int N, int K) {
  constexpr int NT = MT * 2 + 16;           // tiles per K-step (A + B)
  __shared__ __align__(16) char lds[2 * NT * 1024];
  const int t = threadIdx.x;
  const int w = t >> 6, lane = t & 63;
  int lin = blockIdx.y * gridDim.x + blockIdx.x;
  const int nb = gridDim.x * gridDim.y;
  lin = (lin & 7) * (nb >> 3) + (lin >> 3);   // XCD chunked swizzle
  const int shx = 31 - __clz(gridDim.x);      // gridDim.x is pow2 (16 or 4)
  const int bx = lin & (gridDim.x - 1), by = lin >> shx;
  const int quad = lane >> 4, rit = lane & 15;
  const int Mrows = gridDim.y * (MT * 16);
  const size_t psA = (size_t)Mrows * K * 2;
  const size_t psB = (size_t)N * K * 2;
  const int KB = K >> 5;
  const int wm = (w >> 1) * (MT / 2), wn = (w & 1) * 4;

  auto STAGE = [&](char* buf, int kt) {
    char* bufA = buf;
    char* bufB = buf + MT * 2 * 1024;
#pragma unroll
    for (int r = 0; r < MT / 2; r++) {
      int q = w + 4 * r;
      int p = q / MT, tt = q % MT;
      async16(bufA + (p * MT + tt) * 1024,
              AP + p * psA + ((size_t)(by * MT + tt) * KB + kt) * 1024 + lane * 16);
    }
#pragma unroll
    for (int r = 0; r < 4; r++) {
      int q = w + 4 * r;
      int p = q >> 3, tt = q & 7;
      async16(bufB + (p * 8 + tt) * 1024,
              BP + p * psB + ((size_t)(bx * 8 + tt) * KB + kt) * 1024 + lane * 16);
    }
  };

  f32x4 acc[MT / 2][4];
#pragma unroll
  for (int i = 0; i < MT / 2; i++)
#pragma unroll
    for (int j = 0; j < 4; j++) acc[i][j] = (f32x4){0.f, 0.f, 0.f, 0.f};

  // prologue: stage kt=0 and kt=1; wait own-wave oldest batch (kt=0)
  STAGE(lds, 0);
  STAGE(lds + NT * 1024, 1);
  if constexpr (MT == 8) asm volatile("s_waitcnt vmcnt(8)" ::: "memory");
  else                   asm volatile("s_waitcnt vmcnt(6)" ::: "memory");
  __builtin_amdgcn_s_barrier();
  __builtin_amdgcn_sched_barrier(0);

  for (int kt = 0; kt < KB; kt++) {
    char* cb = lds + (kt & 1) * (NT * 1024);
    short8 af[2][MT / 2], bf[2][4];
#pragma unroll
    for (int p = 0; p < 2; p++)
#pragma unroll
      for (int mi = 0; mi < MT / 2; mi++)
        af[p][mi] = *(const short8*)(cb + (p * MT + wm + mi) * 1024 + lane * 16);
#pragma unroll
    for (int ni = 0; ni < 4; ni++) {
      const char* bb = cb + MT * 2 * 1024 + (wn + ni) * 1024 + lane * 16;
      bf[0][ni] = *(const short8*)(bb);
      bf[1][ni] = *(const short8*)(bb + 8192);
    }
    asm volatile("s_waitcnt lgkmcnt(0)" ::: "memory");
    __builtin_amdgcn_sched_barrier(0);
    __builtin_amdgcn_s_barrier();          // all waves done reading cb
    if (kt + 2 < KB) STAGE(cb, kt + 2);    // overwrite cb for kt+2
    __builtin_amdgcn_s_setprio(1);
#pragma unroll
    for (int ni = 0; ni < 4; ni++)
#pragma unroll
      for (int mi = 0; mi < MT / 2; mi++) {
        f32x4 c = acc[mi][ni];
        c = __builtin_amdgcn_mfma_f32_16x16x32_bf16(af[0][mi], bf[0][ni], c, 0, 0, 0);
        c = __builtin_amdgcn_mfma_f32_16x16x32_bf16(af[0][mi], bf[1][ni], c, 0, 0, 0);
        c = __builtin_amdgcn_mfma_f32_16x16x32_bf16(af[1][mi], bf[0][ni], c, 0, 0, 0);
        acc[mi][ni] = c;
      }
    __builtin_amdgcn_s_setprio(0);
    if (kt + 2 < KB) {
      if constexpr (MT == 8) asm volatile("s_waitcnt vmcnt(8)" ::: "memory");
      else                   asm volatile("s_waitcnt vmcnt(6)" ::: "memory");
    } else {
      asm volatile("s_waitcnt vmcnt(0)" ::: "memory");
    }
    __builtin_amdgcn_s_barrier();          // buf[kt+1] ready for all waves
    __builtin_amdgcn_sched_barrier(0);
  }

  const int n0 = bx * 128, m_base = by * (MT * 16);
  if (!PLANES_OUT) {
    float* C = (float*)Cout;
#pragma unroll
    for (int mi = 0; mi < MT / 2; mi++) {
      const int gr0 = m_base + (wm + mi) * 16 + quad * 4;
#pragma unroll
      for (int ni = 0; ni < 4; ni++) {
        const int gc = n0 + (wn + ni) * 16 + rit;
        const float bia = bias[gc];
#pragma unroll
        for (int e = 0; e < 4; e++) {
          float v = acc[mi][ni][e] + bia;
          if (GELU) v = 0.5f * v * (1.0f + erff(v * 0.7071067811865476f));
          C[(size_t)(gr0 + e) * N + gc] = v;
        }
      }
    }
  } else {
    // write gelu output as frag-order planes (M = Mrows, "K" = N)
    char* CP = (char*)Cout;
    const size_t psC = (size_t)Mrows * N * 2;
    float* lf = (float*)lds;   // 128 x 64 fp32 = 32 KB scratch
    for (int h = 0; h < 2; h++) {
      __syncthreads();
      if ((w & 1) == h) {
#pragma unroll
        for (int ni = 0; ni < 4; ni++) {
          const float bia = bias[n0 + h * 64 + ni * 16 + rit];
#pragma unroll
          for (int mi = 0; mi < MT / 2; mi++) {
            const int ml0 = (wm + mi) * 16 + quad * 4;
#pragma unroll
            for (int e = 0; e < 4; e++) {
              float v = acc[mi][ni][e] + bia;
              if (GELU) v = 0.5f * v * (1.0f + erff(v * 0.7071067811865476f));
              lf[(ml0 + e) * 64 + ni * 16 + rit] = v;
            }
          }
        }
      }
      __syncthreads();
#pragma unroll
      for (int it = 0; it < (MT * 16 * 8) / 256; it++) {
        int p = it * 256 + t;
        int ml = p >> 3, n8 = p & 7;
        float4 v0 = *(const float4*)&lf[ml * 64 + n8 * 8];
        float4 v1 = *(const float4*)&lf[ml * 64 + n8 * 8 + 4];
        uint4 H, Md;
        split2u(v0, v1, H, Md);
        int mg = m_base + ml, kg = n0 + h * 64 + n8 * 8;
        size_t off = ((size_t)(mg >> 4) * (N >> 5) + (kg >> 5)) * 1024
                   + (size_t)(((kg >> 3) & 3) * 256 + (mg & 15) * 16);
        *(uint4*)(CP + off) = H;
        *(uint4*)(CP + psC + off) = Md;
      }
    }
  }
}

extern "C" void kernel_launch(void* const* d_in, const int* in_sizes, int n_in,
                              void* d_out, int out_size, void* d_ws, size_t ws_size,
                              hipStream_t stream) {
  const float* x     = (const float*)d_in[0];
  const float* emb_w = (const float*)d_in[1];
  const float* emb_b = (const float*)d_in[2];
  const float* ln1_s = (const float*)d_in[3];
  const float* ln1_b = (const float*)d_in[4];
  const float* w1    = (const float*)d_in[5];
  const float* b1    = (const float*)d_in[6];
  const float* w2    = (const float*)d_in[7];
  const float* b2    = (const float*)d_in[8];
  const float* ln2_s = (const float*)d_in[9];
  const float* ln2_b = (const float*)d_in[10];
  const float* out_w = (const float*)d_in[11];
  const float* out_b = (const float*)d_in[12];
  float* outp = (float*)d_out;

  char* ws = (char*)d_ws;
  if (ws_size < (212ULL << 20)) return;
  float* PE    = (float*)(ws);                    // 8 MiB, dead after embed
  char*  W1S   = ws;                              // 4 MiB planes, overlay PE
  float* BUF[3] = { (float*)(ws + (8ULL << 20)),
                    (float*)(ws + (72ULL << 20)),
                    (float*)(ws + (136ULL << 20)) };  // 3 x 64 MiB
  char*  W2S   = ws + (200ULL << 20);             // 4 MiB planes
  float* MB    = (float*)(ws + (206ULL << 20));   // 1 MiB
  int*   IDX   = (int*)  (ws + (207ULL << 20));
  int*   TOP   = (int*)  (ws + (208ULL << 20));
  float* MEANQ = (float*)(ws + (208ULL << 20) + (64 << 10));
  double* PART = (double*)(ws + (209ULL << 20));  // 1 MiB (64*32*64 fp64)
  char*  FLG   = ws + (210ULL << 20);             // 256 KiB (64 bh x L)
  float* CTX   = (float*)(ws + (210ULL << 20) + (512 << 10));   // 768 KiB

  k_pe<<<256, 256, 0, stream>>>(PE);
  k_embed<<<(8 * 4096) / 16, 256, 0, stream>>>(x, emb_w, emb_b, PE, BUF[0]);

  const int Ls[3] = {4096, 2048, 1024};
  const int Lshs[3] = {12, 11, 10};
  const int us[3] = {45, 40, 35};
  int xi = 0, ai = 1, yi = 2;
  char* FINALP = nullptr;
  for (int layer = 0; layer < 3; layer++) {
    const int L = Ls[layer], u = us[layer];
    float* X = BUF[xi]; float* A = BUF[ai]; float* Y = BUF[yi];

    // per-layer weight planes (PE dead after embed)
    k_splitX<<<(2048 * 512 / 8) / 256, 256, 0, stream>>>(
        w1 + (size_t)layer * 2048 * 512, W1S, 512, 2048 * 512 / 8);
    k_splitX<<<(512 * 2048 / 8) / 256, 256, 0, stream>>>(
        w2 + (size_t)layer * 512 * 2048, W2S, 2048, 512 * 2048 / 8);

    unsigned Ka, Kb, k2a, k2b;
    tf2x32(0u, 42u, 0u, (unsigned)layer, Ka, Kb);
    tf2x32(Ka, Kb, 0u, 1u, k2a, k2b);
    const int n = L * u;
    k_idx<<<(n + 255) / 256, 256, 0, stream>>>(IDX, k2a, k2b, n, L - 1);
    const int S = 32;
    k_colmean1<<<dim3(S, 64), 256, 0, stream>>>(X, PART, L, S);
    k_colmean2<<<64, 64, 0, stream>>>(PART, MEANQ, L, S);
    k_M<<<64 * L / 4, 256, 0, stream>>>(X, IDX, MB, L, Lshs[layer], u,
                                        1.0f / (float)L);
    k_topk<<<64, 256, 0, stream>>>(MB, TOP, L, u);
    hipMemsetAsync(FLG, 0, (size_t)64 * L, stream);
    // S (scores) lives at Y [<48 MiB]; PV partials + stats in Y's tail
    float* P2 = (float*)((char*)Y + (48ULL << 20));   // 6.3 MiB
    float* MS = (float*)((char*)Y + (56ULL << 20));   // 98 KiB
    float* SS = (float*)((char*)Y + (57ULL << 20));   // 98 KiB
    k_scores<<<dim3(L / 64, 64), 256, 0, stream>>>(X, TOP, Y, L, u);
    k_pv<<<dim3(PVSEG, 64), 256, 0, stream>>>(X, Y, P2, MS, SS, L, u);
    k_pvred<<<64, 256, 0, stream>>>(P2, MS, SS, TOP, CTX, FLG, L, u);
    // LN1 in-place + X-planes for ALL chunks directly into A (dead region)
    k_ln1<<<8 * L / 4, 256, 0, stream>>>(X, FLG, CTX, MEANQ,
                                         ln1_s + layer * 512,
                                         ln1_b + layer * 512, (char*)A,
                                         L, Lshs[layer]);

    // FFN in 8192-row super-chunks. YP planes (64 MiB) fill Y entirely.
    // XP[c] pre-written by k_ln1 inside A[c]; gemm2 overwrites A[c] after
    // gemm1[c] consumed it. Chunks are self-contained -> no cross clobber.
    char* YP = (char*)Y;
    const int chunks = (8 * L) / 8192;
    for (int c = 0; c < chunks; c++) {
      float* Ac = A + (size_t)c * 8192 * 512;
      char* XP = (char*)Ac;
      k_gemm6<8, 1, 1><<<dim3(16, 64), 256, 0, stream>>>(
          XP, W1S, b1 + layer * 2048, YP, 2048, 512);
      k_gemm6<4, 0, 0><<<dim3(4, 128), 256, 0, stream>>>(
          YP, W2S, b2 + layer * 512, Ac, 512, 2048);
    }
    if (layer < 2) {
      k_ln2<<<8 * (L / 2) / 4, 256, 0, stream>>>(X, A, ln2_s + layer * 512,
                                                 ln2_b + layer * 512, Y);
    } else {
      // final LN emits planes straight into Y (16 MiB) for the projection
      FINALP = (char*)Y;
      k_ln2p<<<8 * L / 4, 256, 0, stream>>>(X, A, ln2_s + layer * 512,
                                            ln2_b + layer * 512, FINALP);
    }
    int tswap = xi; xi = yi; yi = ai; ai = tswap;  // next X = Y
  }
  // final projection: (8192, 512) @ out_w^T + out_b, planes from k_ln2p
  char* WOS = W2S;                                 // 1 MiB planes
  k_splitX<<<(512 * 512 / 8) / 256, 256, 0, stream>>>(out_w, WOS, 512, 512 * 512 / 8);
  k_gemm6<4, 0, 0><<<dim3(4, 128), 256, 0, stream>>>(
      FINALP, WOS, out_b, outp, 512, 512);
}